// Round 20
// baseline (306.021 us; speedup 1.0000x reference)
//
#include <hip/hip_runtime.h>

// ---------------------------------------------------------------------------
// GConv via  mean_e(concat(x_src, ef) @ W + b) = mean_feats @ W + mask*b
// prep(unit-stride int8 feats + copy left + Wt; NO atomics) ->
// count_ef (fused: coalesced ef->int8 stream + LDS bucket hist) ->
// scanS1 -> scanS2 -> binA_place (atomic-free positions, CHUNK=16K runs) ->
// agg (512 thr / 8 waves; per-node ranks in LDS; int8 feat gather + 16B
// int8 ef reads; bf16 means) -> bf16 MFMA GEMM, bias folded at K=144.
// Zero global atomics anywhere.
// ---------------------------------------------------------------------------

#define N_OP    50000
#define N_DEV   5000
#define N_NODES 160000
#define NB0 0
#define NB1 5000
#define NB2 55000
#define NB3 105000
#define NB4 110000

#define NBUCK   5000     // 32 nodes per bucket
#define BSHIFT  5
#define CHUNK   16384    // edges per bin block (152 blocks @ 1024 thr)
#define STAGE_CAP 4992   // max records per bucket (place worst ~4.1k)

typedef unsigned char  u8;
typedef unsigned short u16;
typedef unsigned int   u32;
typedef __attribute__((ext_vector_type(8))) unsigned short u16x8;
typedef __attribute__((ext_vector_type(2))) unsigned int   u32x2;
typedef __attribute__((ext_vector_type(8))) short          short8;
typedef __attribute__((ext_vector_type(4))) float          f32x4;

__device__ __forceinline__ u16 bf16rn(float x) {
    unsigned u = __float_as_uint(x);
    return (u16)((u + 0x7fffu + ((u >> 16) & 1u)) >> 16);
}

// int8 Q4.4 encode: q = rint(clamp(v,±7.9)*16)
__device__ __forceinline__ u32 q8pack4(float a, float b, float c, float d) {
    int qa = (int)rintf(fminf(fmaxf(a, -7.9f), 7.9f) * 16.f);
    int qb = (int)rintf(fminf(fmaxf(b, -7.9f), 7.9f) * 16.f);
    int qc = (int)rintf(fminf(fmaxf(c, -7.9f), 7.9f) * 16.f);
    int qd = (int)rintf(fminf(fmaxf(d, -7.9f), 7.9f) * 16.f);
    return (u32)(u8)qa | ((u32)(u8)qb << 8) | ((u32)(u8)qc << 16) | ((u32)(u8)qd << 24);
}

// Fused, all unit-stride, NO atomics: feats float4/thread (copy left + int8),
// Wt build (bf16 transposed, bias at k=144).
__global__ __launch_bounds__(256) void prep_kernel(
    const float* __restrict__ opf, const float* __restrict__ devf,
    const float* __restrict__ W0, const float* __restrict__ W1,
    const float* __restrict__ W2, const float* __restrict__ W3,
    const float* __restrict__ W4,
    const float* __restrict__ B0, const float* __restrict__ B1,
    const float* __restrict__ B2, const float* __restrict__ B3,
    const float* __restrict__ B4,
    u8* __restrict__ opb, u8* __restrict__ devb,
    float* __restrict__ out, u16* __restrict__ wtop, u16* __restrict__ wtdev) {
    const int NU0 = (N_OP + N_DEV) * 32;   // feats float4 units
    int t = blockIdx.x * 256 + threadIdx.x;
    if (t < NU0) {
        int row = t >> 5, q = t & 31;
        const float* s; u8* d; size_t lrow;
        if (row < N_OP) { s = opf;  d = opb;  lrow = (size_t)row; }
        else            { s = devf; d = devb; lrow = (size_t)(row - N_OP); }
        float4 x = *(const float4*)&s[lrow * 128 + q * 4];
        *(float4*)&out[(size_t)row * 256 + q * 4] = x;
        *(u32*)&d[lrow * 128 + q * 4] = q8pack4(x.x, x.y, x.z, x.w);
        return;
    }
    t -= NU0;
    if (t < 128 * 480) {   // wtop: segs prev, succ, serve
        int n = t / 480, kk = t % 480, seg = kk / 160, k = kk % 160;
        const float* Ws = (seg == 0) ? W1 : ((seg == 1) ? W2 : W4);
        const float* Bs = (seg == 0) ? B1 : ((seg == 1) ? B2 : B4);
        float v = (k < 144) ? Ws[(size_t)k * 128 + n] : ((k == 144) ? Bs[n] : 0.f);
        wtop[(size_t)n * 480 + kk] = bf16rn(v);
        return;
    }
    t -= 128 * 480;
    if (t >= 128 * 320) return;
    {                      // wtdev: segs link, place
        int n = t / 320, kk = t % 320, seg = kk / 160, k = kk % 160;
        const float* Ws = seg ? W3 : W0;
        const float* Bs = seg ? B3 : B0;
        float v = (k < 144) ? Ws[(size_t)k * 128 + n] : ((k == 144) ? Bs[n] : 0.f);
        wtdev[(size_t)n * 320 + kk] = bf16rn(v);
    }
}

// Fused: coalesced ef->int8 conversion (BW-bound, 64 float4-iters) + LDS
// bucket histogram (latency-bound, rides for free) -> hist[blk][NBUCK].
__global__ __launch_bounds__(1024) void count_ef_kernel(
    const float* __restrict__ ef0, const float* __restrict__ ef1,
    const float* __restrict__ ef2, const float* __restrict__ ef3,
    const float* __restrict__ ef4,
    const int* __restrict__ d0, const int* __restrict__ d1,
    const int* __restrict__ d2, const int* __restrict__ d3,
    const int* __restrict__ d4,
    int e1, int e2, int e3, int e4, int ntot,
    u8* __restrict__ efb8, int* __restrict__ hist) {
    __shared__ u32 cnt2[NBUCK / 2];
    int tid = threadIdx.x;
    int e0 = blockIdx.x * CHUNK;
    for (int i = tid; i < NBUCK / 2; i += 1024) cnt2[i] = 0;
    __syncthreads();
    // ef -> int8: one float4 (quarter-row) per thread, coalesced
    const int q0 = e0 << 2, qtot = ntot << 2;
#pragma unroll 4
    for (int j = 0; j < 64; j++) {
        int t = q0 + j * 1024 + tid;
        if (t < qtot) {
            int e = t >> 2;
            const float* efp; int eb;
            if (e < e1)      { efp = ef0; eb = 0; }
            else if (e < e2) { efp = ef1; eb = e1; }
            else if (e < e3) { efp = ef2; eb = e2; }
            else if (e < e4) { efp = ef3; eb = e3; }
            else             { efp = ef4; eb = e4; }
            float4 f = *(const float4*)&efp[((size_t)(e - eb) << 4) + (t & 3) * 4];
            *(u32*)&efb8[(size_t)t * 4] = q8pack4(f.x, f.y, f.z, f.w);
        }
    }
    // bucket histogram
#pragma unroll
    for (int j = 0; j < 16; j++) {
        int e = e0 + j * 1024 + tid;
        if (e < ntot) {
            const int* dp; int nb, eb;
            if (e < e1)      { dp = d0; nb = NB0; eb = 0; }
            else if (e < e2) { dp = d1; nb = NB1; eb = e1; }
            else if (e < e3) { dp = d2; nb = NB2; eb = e2; }
            else if (e < e4) { dp = d3; nb = NB3; eb = e3; }
            else             { dp = d4; nb = NB4; eb = e4; }
            int b = (nb + dp[e - eb]) >> BSHIFT;
            atomicAdd(&cnt2[b >> 1], 1u << ((b & 1) * 16));
        }
    }
    __syncthreads();
    int* hrow = hist + (size_t)blockIdx.x * NBUCK;
    for (int b = tid; b < NBUCK; b += 1024)
        hrow[b] = (int)((cnt2[b >> 1] >> ((b & 1) * 16)) & 0xffffu);
}

// S1: thread per bucket; convert hist entries to intra-bucket block
// prefixes; write bucket totals.
__global__ __launch_bounds__(256) void scanS1_kernel(
    int* __restrict__ hist, int* __restrict__ totals, int nblk) {
    int b = blockIdx.x * 256 + threadIdx.x;
    if (b >= NBUCK) return;
    int run = 0;
#pragma unroll 4
    for (int blk = 0; blk < nblk; blk++) {
        size_t idx = (size_t)blk * NBUCK + b;
        int t = hist[idx];
        hist[idx] = run;
        run += t;
    }
    totals[b] = run;
}

// S2: single-block exclusive scan of 5000 bucket totals -> bstart[5001].
__global__ __launch_bounds__(1024) void scanS2_kernel(
    const int* __restrict__ totals, int* __restrict__ bstart) {
    __shared__ int wsum[16];
    int t = threadIdx.x;
    int v[5]; int s = 0;
#pragma unroll
    for (int j = 0; j < 5; j++) {
        int idx = t * 5 + j;
        v[j] = (idx < NBUCK) ? totals[idx] : 0;
        s += v[j];
    }
    int lane = t & 63, wid = t >> 6;
    int incl = s;
#pragma unroll
    for (int off = 1; off < 64; off <<= 1) {
        int x = __shfl_up(incl, off, 64);
        if (lane >= off) incl += x;
    }
    if (lane == 63) wsum[wid] = incl;
    __syncthreads();
    int woff = 0;
    for (int w = 0; w < wid; w++) woff += wsum[w];
    int run = woff + incl - s;
#pragma unroll
    for (int j = 0; j < 5; j++) {
        int idx = t * 5 + j;
        if (idx < NBUCK) bstart[idx] = run;
        run += v[j];
    }
    if (t == 1023) bstart[NBUCK] = run;
}

// Place pass: base[b] = bstart[b] + hist[blk][b]; LDS rank only (no global
// atomics). 8B records (src|nl<<16, global_e). CHUNK=16K keeps per-bucket
// runs long -> low partial-line write amplification.
__global__ __launch_bounds__(1024) void binA_place_kernel(
    const int* __restrict__ s0p, const int* __restrict__ s1p,
    const int* __restrict__ s2p, const int* __restrict__ s3p,
    const int* __restrict__ s4p,
    const int* __restrict__ d0, const int* __restrict__ d1,
    const int* __restrict__ d2, const int* __restrict__ d3,
    const int* __restrict__ d4,
    int e1, int e2, int e3, int e4, int ntot,
    const int* __restrict__ hist, const int* __restrict__ bstart,
    int2* __restrict__ edata) {
    __shared__ u32 cnt2[NBUCK / 2];   // 10KB
    __shared__ int base[NBUCK];       // 20KB
    int tid = threadIdx.x;
    int e0 = blockIdx.x * CHUNK;
    for (int i = tid; i < NBUCK / 2; i += 1024) cnt2[i] = 0;
    __syncthreads();
    int myg[16];
#pragma unroll
    for (int j = 0; j < 16; j++) {
        int e = e0 + j * 1024 + tid;
        int g = -1;
        if (e < ntot) {
            const int* dp; int nb, eb;
            if (e < e1)      { dp = d0; nb = NB0; eb = 0; }
            else if (e < e2) { dp = d1; nb = NB1; eb = e1; }
            else if (e < e3) { dp = d2; nb = NB2; eb = e2; }
            else if (e < e4) { dp = d3; nb = NB3; eb = e3; }
            else             { dp = d4; nb = NB4; eb = e4; }
            g = nb + dp[e - eb];
            int b = g >> BSHIFT;
            atomicAdd(&cnt2[b >> 1], 1u << ((b & 1) * 16));
        }
        myg[j] = g;
    }
    __syncthreads();
    const int* hrow = hist + (size_t)blockIdx.x * NBUCK;
    for (int b = tid; b < NBUCK; b += 1024)
        base[b] = bstart[b] + hrow[b];
    __syncthreads();
#pragma unroll
    for (int j = 0; j < 16; j++) {
        int g = myg[j];
        if (g < 0) continue;
        int e = e0 + j * 1024 + tid;
        const int* sp; int eb;
        if (e < e1)      { sp = s0p; eb = 0; }
        else if (e < e2) { sp = s1p; eb = e1; }
        else if (e < e3) { sp = s2p; eb = e2; }
        else if (e < e4) { sp = s3p; eb = e3; }
        else             { sp = s4p; eb = e4; }
        int el = e - eb;
        int b = g >> BSHIFT;
        u32 old = atomicSub(&cnt2[b >> 1], 1u << ((b & 1) * 16));
        int myc = (int)((old >> ((b & 1) * 16)) & 0xffffu);
        int pos = base[b] + myc - 1;
        edata[pos] = make_int2((int)((u32)sp[el] | ((u32)(g & 31) << 16)), e);
    }
}

// Fused binB+agg: one block per bucket, 512 threads = 8 waves (wave ceiling
// 32/CU). Stage (u16 src, int global_e) at exact per-node ranks in LDS
// (30KB), then 8 waves x 4 nodes gather int8 feats (L2/L3) + 16B int8 ef
// rows, 4x8-chain ILP. Round-17 proven form (scalar unpack).
// Sources: link dev->dev, prev/succ op->op, place op->dev, serve dev->op.
__global__ __launch_bounds__(512) void agg_fused_kernel(
    const u8* __restrict__ opb, const u8* __restrict__ devb,
    const u8* __restrict__ efb8,
    const int2* __restrict__ edata, const int* __restrict__ bstart,
    u16* __restrict__ agg) {
    __shared__ u16 s_src[STAGE_CAP];
    __shared__ int s_e[STAGE_CAP];
    __shared__ int s_cnt[32], s_off[32], s_cur[32];
    int bid = blockIdx.x, tid = threadIdx.x;
    // bijective remap: place buckets (3281..3437) first, link (0..156) next
    int b;
    if (bid < 157)      b = 3281 + bid;
    else if (bid < 314) b = bid - 157;
    else { int t = bid - 314 + 157; b = (t >= 3281) ? t + 157 : t; }
    int n0 = b << BSHIFT;
    int bs = bstart[b];
    int cnt = bstart[b + 1] - bs;
    if (tid < 32) s_cnt[tid] = 0;
    __syncthreads();
    for (int i = tid; i < cnt; i += 512) {
        int l = ((u32)edata[bs + i].x >> 16) & 31;
        atomicAdd(&s_cnt[l], 1);
    }
    __syncthreads();
    if (tid < 32) {
        int v = s_cnt[tid];
        int incl = v;
#pragma unroll
        for (int off = 1; off < 32; off <<= 1) {
            int x = __shfl_up(incl, off, 64);
            if (tid >= off) incl += x;
        }
        s_off[tid] = incl - v;
        s_cur[tid] = incl - v;
    }
    __syncthreads();
    for (int i = tid; i < cnt; i += 512) {
        int2 r = edata[bs + i];
        int l = ((u32)r.x >> 16) & 31;
        int rank = atomicAdd(&s_cur[l], 1);
        if (rank < STAGE_CAP) {
            s_src[rank] = (u16)r.x;
            s_e[rank] = r.y;
        }
    }
    __syncthreads();
    int wave = tid >> 6, lane = tid & 63;
    int grp = lane >> 4, gl = lane & 15;
    for (int ni = 0; ni < 4; ni++) {
        int nl = wave * 4 + ni;
        int w = n0 + nl;
        // src feats: device for link [0,NB1) and serve [NB4,..); op otherwise
        const u8* sf = (w < NB1 || w >= NB4) ? devb : opb;
        int dg = s_cnt[nl];
        int lo = s_off[nl];
        float a0 = 0.f, a1 = 0.f, a2 = 0.f, a3 = 0.f;
        float a4 = 0.f, a5 = 0.f, a6 = 0.f, a7 = 0.f;
        float aef = 0.f;
        for (int bb = 0; bb < dg; bb += 32) {
            u32 srcs[8]; int eids[8];
#pragma unroll
            for (int k = 0; k < 8; k++) {
                int idx = bb + k * 4 + grp;
                if (idx < dg) { srcs[k] = s_src[lo + idx]; eids[k] = s_e[lo + idx]; }
                else          { eids[k] = -1; }
            }
#pragma unroll
            for (int k = 0; k < 8; k++) {
                if (eids[k] >= 0) {
                    u32x2 f = *(const u32x2*)&sf[(size_t)srcs[k] * 128 + gl * 8];
                    a0 += (float)(int)(signed char)(u8)(f[0]);
                    a1 += (float)(int)(signed char)(u8)(f[0] >> 8);
                    a2 += (float)(int)(signed char)(u8)(f[0] >> 16);
                    a3 += (float)(int)(signed char)(u8)(f[0] >> 24);
                    a4 += (float)(int)(signed char)(u8)(f[1]);
                    a5 += (float)(int)(signed char)(u8)(f[1] >> 8);
                    a6 += (float)(int)(signed char)(u8)(f[1] >> 16);
                    a7 += (float)(int)(signed char)(u8)(f[1] >> 24);
                    aef += (float)(int)(signed char)efb8[(size_t)eids[k] * 16 + gl];
                }
            }
        }
#define RED(x) x += __shfl_xor(x, 16); x += __shfl_xor(x, 32);
        RED(a0) RED(a1) RED(a2) RED(a3) RED(a4) RED(a5) RED(a6) RED(a7) RED(aef)
#undef RED
        float inv = (dg > 0) ? 1.f / (float)dg : 0.f;
        float s = 0.0625f * inv;     // Q4.4 descale folded into mean
        u16* row = &agg[(size_t)w * 160];
        if (lane < 16) {
            u16x8 o;
            o[0] = bf16rn(a0 * s); o[1] = bf16rn(a1 * s);
            o[2] = bf16rn(a2 * s); o[3] = bf16rn(a3 * s);
            o[4] = bf16rn(a4 * s); o[5] = bf16rn(a5 * s);
            o[6] = bf16rn(a6 * s); o[7] = bf16rn(a7 * s);
            *(u16x8*)&row[gl * 8] = o;
            row[128 + gl] = bf16rn(aef * s);
        } else if (lane < 32) {
            int g2 = lane - 16;
            row[144 + g2] = (g2 == 0 && dg > 0) ? (u16)0x3F80 : (u16)0;
        }
    }
}

// bf16 MFMA GEMM: block = 4 waves, 64 rows x 128 cols. Wave holds 16 rows,
// 8 col-tiles (acc f32x4 x8). Epilogue relu(acc*scale); bias via K=144 slot.
__global__ __launch_bounds__(256) void gemm_mfma_kernel(
    const u16* __restrict__ aggb, const u16* __restrict__ wtop,
    const u16* __restrict__ wtdev, float* __restrict__ out, int opblocks) {
    int bid = blockIdx.x, tid = threadIdx.x;
    int wave = tid >> 6, lane = tid & 63;
    bool isop = bid < opblocks;
    int rowbase, ndst, nseg, outrow0, Kpad, sb0, sb1, sb2;
    const u16* Wt; float scale;
    if (isop) {
        rowbase = bid * 64; ndst = N_OP; nseg = 3; outrow0 = 0;
        Kpad = 480; Wt = wtop; scale = 1.f / 3.f;
        sb0 = NB1; sb1 = NB2; sb2 = NB4;
    } else {
        rowbase = (bid - opblocks) * 64; ndst = N_DEV; nseg = 2; outrow0 = N_OP;
        Kpad = 320; Wt = wtdev; scale = 0.5f;
        sb0 = NB0; sb1 = NB3; sb2 = NB3;
    }
    int r16 = rowbase + wave * 16 + (lane & 15);
    int ar = min(r16, ndst - 1);
    int kq = (lane >> 4) * 8;
    f32x4 acc[8];
#pragma unroll
    for (int nt = 0; nt < 8; nt++) acc[nt] = (f32x4){0.f, 0.f, 0.f, 0.f};

    const u16* wbase = Wt + (size_t)(lane & 15) * Kpad + kq;
    for (int seg = 0; seg < nseg; seg++) {
        int segbase = (seg == 0) ? sb0 : ((seg == 1) ? sb1 : sb2);
        const u16* ap = aggb + (size_t)(segbase + ar) * 160 + kq;
        const u16* wp = wbase + seg * 160;
        for (int k0 = 0; k0 < 160; k0 += 32) {
            short8 a = *(const short8*)(ap + k0);
#pragma unroll
            for (int nt = 0; nt < 8; nt++) {
                short8 b = *(const short8*)(wp + (size_t)nt * 16 * Kpad + k0);
                acc[nt] = __builtin_amdgcn_mfma_f32_16x16x32_bf16(a, b, acc[nt], 0, 0, 0);
            }
        }
    }

    int colb = lane & 15;
    int rowe = rowbase + wave * 16 + (lane >> 4) * 4;
#pragma unroll
    for (int nt = 0; nt < 8; nt++) {
#pragma unroll
        for (int r = 0; r < 4; r++) {
            int row = rowe + r;
            if (row < ndst)
                out[(size_t)(outrow0 + row) * 256 + 128 + nt * 16 + colb] =
                    fmaxf(acc[nt][r] * scale, 0.f);
        }
    }
}

extern "C" void kernel_launch(void* const* d_in, const int* in_sizes, int n_in,
                              void* d_out, int out_size, void* d_ws, size_t ws_size,
                              hipStream_t stream) {
    const float* opf  = (const float*)d_in[0];
    const float* devf = (const float*)d_in[1];
    const float* ef[5]; const int* src[5]; const int* dst[5];
    const float* W[5]; const float* bias[5];
    int ne[5];
    for (int i = 0; i < 5; i++) {
        ef[i]   = (const float*)d_in[2 + 5 * i + 0];
        src[i]  = (const int*)  d_in[2 + 5 * i + 1];
        dst[i]  = (const int*)  d_in[2 + 5 * i + 2];
        W[i]    = (const float*)d_in[2 + 5 * i + 3];
        bias[i] = (const float*)d_in[2 + 5 * i + 4];
        ne[i]   = in_sizes[2 + 5 * i + 1];
    }
    int e1 = ne[0], e2 = e1 + ne[1], e3 = e2 + ne[2], e4 = e3 + ne[3];
    int ntot = e4 + ne[4];
    int ntot_pad = (ntot + 1) & ~1;
    int nblk = (ntot + CHUNK - 1) / CHUNK;

    char* wp = (char*)d_ws;
    int* bstart = (int*)wp;  wp += (size_t)(NBUCK + 1) * 4;
    int* totals = (int*)wp;  wp += (size_t)NBUCK * 4;
    wp += 4;                                   // align to 8
    int* hist   = (int*)wp;  wp += (size_t)nblk * NBUCK * 4;
    wp = (char*)(((size_t)wp + 7) & ~7);
    int2* edata = (int2*)wp; wp += (size_t)ntot_pad * 8;
    u16* aggb   = (u16*)wp;  wp += (size_t)N_NODES * 160 * 2;
    u8* opb     = (u8*)wp;   wp += (size_t)N_OP * 128;
    u8* devb    = (u8*)wp;   wp += (size_t)N_DEV * 128;
    u8* efb8    = (u8*)wp;   wp += (size_t)ntot_pad * 16;
    u16* wtop   = (u16*)wp;  wp += (size_t)128 * 480 * 2;
    u16* wtdev  = (u16*)wp;
    float* out  = (float*)d_out;

    const int NU = (N_OP + N_DEV) * 32 + 128 * 800;  // feats quads + wt units
    prep_kernel<<<(NU + 255) / 256, 256, 0, stream>>>(
        opf, devf, W[0], W[1], W[2], W[3], W[4],
        bias[0], bias[1], bias[2], bias[3], bias[4],
        opb, devb, out, wtop, wtdev);

    count_ef_kernel<<<nblk, 1024, 0, stream>>>(
        ef[0], ef[1], ef[2], ef[3], ef[4],
        dst[0], dst[1], dst[2], dst[3], dst[4],
        e1, e2, e3, e4, ntot, efb8, hist);

    scanS1_kernel<<<(NBUCK + 255) / 256, 256, 0, stream>>>(hist, totals, nblk);
    scanS2_kernel<<<1, 1024, 0, stream>>>(totals, bstart);

    binA_place_kernel<<<nblk, 1024, 0, stream>>>(
        src[0], src[1], src[2], src[3], src[4],
        dst[0], dst[1], dst[2], dst[3], dst[4],
        e1, e2, e3, e4, ntot, hist, bstart, edata);

    agg_fused_kernel<<<NBUCK, 512, 0, stream>>>(
        opb, devb, efb8, edata, bstart, aggb);

    int opblocks = (N_OP + 63) / 64, devblocks = (N_DEV + 63) / 64;
    gemm_mfma_kernel<<<opblocks + devblocks, 256, 0, stream>>>(
        aggb, wtop, wtdev, out, opblocks);
    (void)n_in; (void)out_size; (void)ws_size;
}

// Round 21
// 281.523 us; speedup vs baseline: 1.0870x; 1.0870x over previous
//
#include <hip/hip_runtime.h>

// ---------------------------------------------------------------------------
// GConv via  mean_e(concat(x_src, ef) @ W + b) = mean_feats @ W + mask*b
// prep(unit-stride int8 feats + int8 ef + copy left + Wt; NO atomics) ->
// binA_count (LDS bucket hist, CHUNK=16K) -> scanS1 -> scanS2 ->
// binA_place (atomic-free positions, long runs -> low write amp) ->
// agg (512 thr / 8 waves; per-node ranks in LDS; int8 feat gather + 16B
// int8 ef reads; bf16 means) -> bf16 MFMA GEMM, bias folded at K=144.
// Zero global atomics anywhere.
// ---------------------------------------------------------------------------

#define N_OP    50000
#define N_DEV   5000
#define N_NODES 160000
#define NB0 0
#define NB1 5000
#define NB2 55000
#define NB3 105000
#define NB4 110000

#define NBUCK   5000     // 32 nodes per bucket
#define BSHIFT  5
#define CHUNK   16384    // edges per bin block (152 blocks @ 1024 thr)
#define STAGE_CAP 4992   // max records per bucket (place worst ~4.1k)

typedef unsigned char  u8;
typedef unsigned short u16;
typedef unsigned int   u32;
typedef __attribute__((ext_vector_type(8))) unsigned short u16x8;
typedef __attribute__((ext_vector_type(2))) unsigned int   u32x2;
typedef __attribute__((ext_vector_type(8))) short          short8;
typedef __attribute__((ext_vector_type(4))) float          f32x4;

__device__ __forceinline__ u16 bf16rn(float x) {
    unsigned u = __float_as_uint(x);
    return (u16)((u + 0x7fffu + ((u >> 16) & 1u)) >> 16);
}

// int8 Q4.4 encode: q = rint(clamp(v,±7.9)*16)
__device__ __forceinline__ u32 q8pack4(float a, float b, float c, float d) {
    int qa = (int)rintf(fminf(fmaxf(a, -7.9f), 7.9f) * 16.f);
    int qb = (int)rintf(fminf(fmaxf(b, -7.9f), 7.9f) * 16.f);
    int qc = (int)rintf(fminf(fmaxf(c, -7.9f), 7.9f) * 16.f);
    int qd = (int)rintf(fminf(fmaxf(d, -7.9f), 7.9f) * 16.f);
    return (u32)(u8)qa | ((u32)(u8)qb << 8) | ((u32)(u8)qc << 16) | ((u32)(u8)qd << 24);
}

// Fused, all unit-stride, NO atomics: feats float4/thread (copy left + int8),
// ef float4/thread (int8), Wt build (bf16 transposed, bias at k=144).
__global__ __launch_bounds__(256) void prep_kernel(
    const float* __restrict__ opf, const float* __restrict__ devf,
    const float* __restrict__ W0, const float* __restrict__ W1,
    const float* __restrict__ W2, const float* __restrict__ W3,
    const float* __restrict__ W4,
    const float* __restrict__ B0, const float* __restrict__ B1,
    const float* __restrict__ B2, const float* __restrict__ B3,
    const float* __restrict__ B4,
    const float* __restrict__ ef0, const float* __restrict__ ef1,
    const float* __restrict__ ef2, const float* __restrict__ ef3,
    const float* __restrict__ ef4,
    int e1, int e2, int e3, int e4, int ntot,
    u8* __restrict__ opb, u8* __restrict__ devb, u8* __restrict__ efb8,
    float* __restrict__ out, u16* __restrict__ wtop, u16* __restrict__ wtdev) {
    const int NU0 = (N_OP + N_DEV) * 32;   // feats float4 units
    const int NU2 = 128 * 480 + 128 * 320; // wt elems
    int t = blockIdx.x * 256 + threadIdx.x;
    if (t < NU0) {
        int row = t >> 5, q = t & 31;
        const float* s; u8* d; size_t lrow;
        if (row < N_OP) { s = opf;  d = opb;  lrow = (size_t)row; }
        else            { s = devf; d = devb; lrow = (size_t)(row - N_OP); }
        float4 x = *(const float4*)&s[lrow * 128 + q * 4];
        *(float4*)&out[(size_t)row * 256 + q * 4] = x;
        *(u32*)&d[lrow * 128 + q * 4] = q8pack4(x.x, x.y, x.z, x.w);
        return;
    }
    t -= NU0;
    if (t < NU2) {
        if (t < 128 * 480) {   // wtop: segs prev, succ, serve
            int n = t / 480, kk = t % 480, seg = kk / 160, k = kk % 160;
            const float* Ws = (seg == 0) ? W1 : ((seg == 1) ? W2 : W4);
            const float* Bs = (seg == 0) ? B1 : ((seg == 1) ? B2 : B4);
            float v = (k < 144) ? Ws[(size_t)k * 128 + n] : ((k == 144) ? Bs[n] : 0.f);
            wtop[(size_t)n * 480 + kk] = bf16rn(v);
        } else {               // wtdev: segs link, place
            int q = t - 128 * 480;
            int n = q / 320, kk = q % 320, seg = kk / 160, k = kk % 160;
            const float* Ws = seg ? W3 : W0;
            const float* Bs = seg ? B3 : B0;
            float v = (k < 144) ? Ws[(size_t)k * 128 + n] : ((k == 144) ? Bs[n] : 0.f);
            wtdev[(size_t)n * 320 + kk] = bf16rn(v);
        }
        return;
    }
    t -= NU2;
    if (t >= ntot * 4) return; // ef -> int8, one float4 (quarter-row) per thread
    int e = t >> 2;
    const float* efp; int eb;
    if (e < e1)      { efp = ef0; eb = 0; }
    else if (e < e2) { efp = ef1; eb = e1; }
    else if (e < e3) { efp = ef2; eb = e2; }
    else if (e < e4) { efp = ef3; eb = e3; }
    else             { efp = ef4; eb = e4; }
    float4 f = *(const float4*)&efp[((size_t)(e - eb) << 4) + (t & 3) * 4];
    *(u32*)&efb8[(size_t)t * 4] = q8pack4(f.x, f.y, f.z, f.w);
}

// Count pass: per-block LDS bucket histogram -> hist[blk][NBUCK].
__global__ __launch_bounds__(1024) void binA_count_kernel(
    const int* __restrict__ d0, const int* __restrict__ d1,
    const int* __restrict__ d2, const int* __restrict__ d3,
    const int* __restrict__ d4,
    int e1, int e2, int e3, int e4, int ntot, int* __restrict__ hist) {
    __shared__ u32 cnt2[NBUCK / 2];
    int tid = threadIdx.x;
    int e0 = blockIdx.x * CHUNK;
    for (int i = tid; i < NBUCK / 2; i += 1024) cnt2[i] = 0;
    __syncthreads();
#pragma unroll
    for (int j = 0; j < 16; j++) {
        int e = e0 + j * 1024 + tid;
        if (e < ntot) {
            const int* dp; int nb, eb;
            if (e < e1)      { dp = d0; nb = NB0; eb = 0; }
            else if (e < e2) { dp = d1; nb = NB1; eb = e1; }
            else if (e < e3) { dp = d2; nb = NB2; eb = e2; }
            else if (e < e4) { dp = d3; nb = NB3; eb = e3; }
            else             { dp = d4; nb = NB4; eb = e4; }
            int b = (nb + dp[e - eb]) >> BSHIFT;
            atomicAdd(&cnt2[b >> 1], 1u << ((b & 1) * 16));
        }
    }
    __syncthreads();
    int* hrow = hist + (size_t)blockIdx.x * NBUCK;
    for (int b = tid; b < NBUCK; b += 1024)
        hrow[b] = (int)((cnt2[b >> 1] >> ((b & 1) * 16)) & 0xffffu);
}

// S1: thread per bucket; convert hist entries to intra-bucket block
// prefixes; write bucket totals.
__global__ __launch_bounds__(256) void scanS1_kernel(
    int* __restrict__ hist, int* __restrict__ totals, int nblk) {
    int b = blockIdx.x * 256 + threadIdx.x;
    if (b >= NBUCK) return;
    int run = 0;
#pragma unroll 4
    for (int blk = 0; blk < nblk; blk++) {
        size_t idx = (size_t)blk * NBUCK + b;
        int t = hist[idx];
        hist[idx] = run;
        run += t;
    }
    totals[b] = run;
}

// S2: single-block exclusive scan of 5000 bucket totals -> bstart[5001].
__global__ __launch_bounds__(1024) void scanS2_kernel(
    const int* __restrict__ totals, int* __restrict__ bstart) {
    __shared__ int wsum[16];
    int t = threadIdx.x;
    int v[5]; int s = 0;
#pragma unroll
    for (int j = 0; j < 5; j++) {
        int idx = t * 5 + j;
        v[j] = (idx < NBUCK) ? totals[idx] : 0;
        s += v[j];
    }
    int lane = t & 63, wid = t >> 6;
    int incl = s;
#pragma unroll
    for (int off = 1; off < 64; off <<= 1) {
        int x = __shfl_up(incl, off, 64);
        if (lane >= off) incl += x;
    }
    if (lane == 63) wsum[wid] = incl;
    __syncthreads();
    int woff = 0;
    for (int w = 0; w < wid; w++) woff += wsum[w];
    int run = woff + incl - s;
#pragma unroll
    for (int j = 0; j < 5; j++) {
        int idx = t * 5 + j;
        if (idx < NBUCK) bstart[idx] = run;
        run += v[j];
    }
    if (t == 1023) bstart[NBUCK] = run;
}

// Place pass: base[b] = bstart[b] + hist[blk][b]; LDS rank only (no global
// atomics). 8B records (src|nl<<16, global_e). CHUNK=16K doubles per-bucket
// run length -> halves partial-line write amplification.
__global__ __launch_bounds__(1024) void binA_place_kernel(
    const int* __restrict__ s0p, const int* __restrict__ s1p,
    const int* __restrict__ s2p, const int* __restrict__ s3p,
    const int* __restrict__ s4p,
    const int* __restrict__ d0, const int* __restrict__ d1,
    const int* __restrict__ d2, const int* __restrict__ d3,
    const int* __restrict__ d4,
    int e1, int e2, int e3, int e4, int ntot,
    const int* __restrict__ hist, const int* __restrict__ bstart,
    int2* __restrict__ edata) {
    __shared__ u32 cnt2[NBUCK / 2];   // 10KB
    __shared__ int base[NBUCK];       // 20KB
    int tid = threadIdx.x;
    int e0 = blockIdx.x * CHUNK;
    for (int i = tid; i < NBUCK / 2; i += 1024) cnt2[i] = 0;
    __syncthreads();
    int myg[16];
#pragma unroll
    for (int j = 0; j < 16; j++) {
        int e = e0 + j * 1024 + tid;
        int g = -1;
        if (e < ntot) {
            const int* dp; int nb, eb;
            if (e < e1)      { dp = d0; nb = NB0; eb = 0; }
            else if (e < e2) { dp = d1; nb = NB1; eb = e1; }
            else if (e < e3) { dp = d2; nb = NB2; eb = e2; }
            else if (e < e4) { dp = d3; nb = NB3; eb = e3; }
            else             { dp = d4; nb = NB4; eb = e4; }
            g = nb + dp[e - eb];
            int b = g >> BSHIFT;
            atomicAdd(&cnt2[b >> 1], 1u << ((b & 1) * 16));
        }
        myg[j] = g;
    }
    __syncthreads();
    const int* hrow = hist + (size_t)blockIdx.x * NBUCK;
    for (int b = tid; b < NBUCK; b += 1024)
        base[b] = bstart[b] + hrow[b];
    __syncthreads();
#pragma unroll
    for (int j = 0; j < 16; j++) {
        int g = myg[j];
        if (g < 0) continue;
        int e = e0 + j * 1024 + tid;
        const int* sp; int eb;
        if (e < e1)      { sp = s0p; eb = 0; }
        else if (e < e2) { sp = s1p; eb = e1; }
        else if (e < e3) { sp = s2p; eb = e2; }
        else if (e < e4) { sp = s3p; eb = e3; }
        else             { sp = s4p; eb = e4; }
        int el = e - eb;
        int b = g >> BSHIFT;
        u32 old = atomicSub(&cnt2[b >> 1], 1u << ((b & 1) * 16));
        int myc = (int)((old >> ((b & 1) * 16)) & 0xffffu);
        int pos = base[b] + myc - 1;
        edata[pos] = make_int2((int)((u32)sp[el] | ((u32)(g & 31) << 16)), e);
    }
}

// Fused binB+agg: one block per bucket, 512 threads = 8 waves (wave ceiling
// 32/CU). Stage (u16 src, int global_e) at exact per-node ranks in LDS
// (30KB), then 8 waves x 4 nodes gather int8 feats (L2/L3) + 16B int8 ef
// rows, 4x8-chain ILP. Round-17 proven form (scalar unpack).
// Sources: link dev->dev, prev/succ op->op, place op->dev, serve dev->op.
__global__ __launch_bounds__(512) void agg_fused_kernel(
    const u8* __restrict__ opb, const u8* __restrict__ devb,
    const u8* __restrict__ efb8,
    const int2* __restrict__ edata, const int* __restrict__ bstart,
    u16* __restrict__ agg) {
    __shared__ u16 s_src[STAGE_CAP];
    __shared__ int s_e[STAGE_CAP];
    __shared__ int s_cnt[32], s_off[32], s_cur[32];
    int bid = blockIdx.x, tid = threadIdx.x;
    // bijective remap: place buckets (3281..3437) first, link (0..156) next
    int b;
    if (bid < 157)      b = 3281 + bid;
    else if (bid < 314) b = bid - 157;
    else { int t = bid - 314 + 157; b = (t >= 3281) ? t + 157 : t; }
    int n0 = b << BSHIFT;
    int bs = bstart[b];
    int cnt = bstart[b + 1] - bs;
    if (tid < 32) s_cnt[tid] = 0;
    __syncthreads();
    for (int i = tid; i < cnt; i += 512) {
        int l = ((u32)edata[bs + i].x >> 16) & 31;
        atomicAdd(&s_cnt[l], 1);
    }
    __syncthreads();
    if (tid < 32) {
        int v = s_cnt[tid];
        int incl = v;
#pragma unroll
        for (int off = 1; off < 32; off <<= 1) {
            int x = __shfl_up(incl, off, 64);
            if (tid >= off) incl += x;
        }
        s_off[tid] = incl - v;
        s_cur[tid] = incl - v;
    }
    __syncthreads();
    for (int i = tid; i < cnt; i += 512) {
        int2 r = edata[bs + i];
        int l = ((u32)r.x >> 16) & 31;
        int rank = atomicAdd(&s_cur[l], 1);
        if (rank < STAGE_CAP) {
            s_src[rank] = (u16)r.x;
            s_e[rank] = r.y;
        }
    }
    __syncthreads();
    int wave = tid >> 6, lane = tid & 63;
    int grp = lane >> 4, gl = lane & 15;
    for (int ni = 0; ni < 4; ni++) {
        int nl = wave * 4 + ni;
        int w = n0 + nl;
        // src feats: device for link [0,NB1) and serve [NB4,..); op otherwise
        const u8* sf = (w < NB1 || w >= NB4) ? devb : opb;
        int dg = s_cnt[nl];
        int lo = s_off[nl];
        float a0 = 0.f, a1 = 0.f, a2 = 0.f, a3 = 0.f;
        float a4 = 0.f, a5 = 0.f, a6 = 0.f, a7 = 0.f;
        float aef = 0.f;
        for (int bb = 0; bb < dg; bb += 32) {
            u32 srcs[8]; int eids[8];
#pragma unroll
            for (int k = 0; k < 8; k++) {
                int idx = bb + k * 4 + grp;
                if (idx < dg) { srcs[k] = s_src[lo + idx]; eids[k] = s_e[lo + idx]; }
                else          { eids[k] = -1; }
            }
#pragma unroll
            for (int k = 0; k < 8; k++) {
                if (eids[k] >= 0) {
                    u32x2 f = *(const u32x2*)&sf[(size_t)srcs[k] * 128 + gl * 8];
                    a0 += (float)(int)(signed char)(u8)(f[0]);
                    a1 += (float)(int)(signed char)(u8)(f[0] >> 8);
                    a2 += (float)(int)(signed char)(u8)(f[0] >> 16);
                    a3 += (float)(int)(signed char)(u8)(f[0] >> 24);
                    a4 += (float)(int)(signed char)(u8)(f[1]);
                    a5 += (float)(int)(signed char)(u8)(f[1] >> 8);
                    a6 += (float)(int)(signed char)(u8)(f[1] >> 16);
                    a7 += (float)(int)(signed char)(u8)(f[1] >> 24);
                    aef += (float)(int)(signed char)efb8[(size_t)eids[k] * 16 + gl];
                }
            }
        }
#define RED(x) x += __shfl_xor(x, 16); x += __shfl_xor(x, 32);
        RED(a0) RED(a1) RED(a2) RED(a3) RED(a4) RED(a5) RED(a6) RED(a7) RED(aef)
#undef RED
        float inv = (dg > 0) ? 1.f / (float)dg : 0.f;
        float s = 0.0625f * inv;     // Q4.4 descale folded into mean
        u16* row = &agg[(size_t)w * 160];
        if (lane < 16) {
            u16x8 o;
            o[0] = bf16rn(a0 * s); o[1] = bf16rn(a1 * s);
            o[2] = bf16rn(a2 * s); o[3] = bf16rn(a3 * s);
            o[4] = bf16rn(a4 * s); o[5] = bf16rn(a5 * s);
            o[6] = bf16rn(a6 * s); o[7] = bf16rn(a7 * s);
            *(u16x8*)&row[gl * 8] = o;
            row[128 + gl] = bf16rn(aef * s);
        } else if (lane < 32) {
            int g2 = lane - 16;
            row[144 + g2] = (g2 == 0 && dg > 0) ? (u16)0x3F80 : (u16)0;
        }
    }
}

// bf16 MFMA GEMM: block = 4 waves, 64 rows x 128 cols. Wave holds 16 rows,
// 8 col-tiles (acc f32x4 x8). Epilogue relu(acc*scale); bias via K=144 slot.
__global__ __launch_bounds__(256) void gemm_mfma_kernel(
    const u16* __restrict__ aggb, const u16* __restrict__ wtop,
    const u16* __restrict__ wtdev, float* __restrict__ out, int opblocks) {
    int bid = blockIdx.x, tid = threadIdx.x;
    int wave = tid >> 6, lane = tid & 63;
    bool isop = bid < opblocks;
    int rowbase, ndst, nseg, outrow0, Kpad, sb0, sb1, sb2;
    const u16* Wt; float scale;
    if (isop) {
        rowbase = bid * 64; ndst = N_OP; nseg = 3; outrow0 = 0;
        Kpad = 480; Wt = wtop; scale = 1.f / 3.f;
        sb0 = NB1; sb1 = NB2; sb2 = NB4;
    } else {
        rowbase = (bid - opblocks) * 64; ndst = N_DEV; nseg = 2; outrow0 = N_OP;
        Kpad = 320; Wt = wtdev; scale = 0.5f;
        sb0 = NB0; sb1 = NB3; sb2 = NB3;
    }
    int r16 = rowbase + wave * 16 + (lane & 15);
    int ar = min(r16, ndst - 1);
    int kq = (lane >> 4) * 8;
    f32x4 acc[8];
#pragma unroll
    for (int nt = 0; nt < 8; nt++) acc[nt] = (f32x4){0.f, 0.f, 0.f, 0.f};

    const u16* wbase = Wt + (size_t)(lane & 15) * Kpad + kq;
    for (int seg = 0; seg < nseg; seg++) {
        int segbase = (seg == 0) ? sb0 : ((seg == 1) ? sb1 : sb2);
        const u16* ap = aggb + (size_t)(segbase + ar) * 160 + kq;
        const u16* wp = wbase + seg * 160;
        for (int k0 = 0; k0 < 160; k0 += 32) {
            short8 a = *(const short8*)(ap + k0);
#pragma unroll
            for (int nt = 0; nt < 8; nt++) {
                short8 b = *(const short8*)(wp + (size_t)nt * 16 * Kpad + k0);
                acc[nt] = __builtin_amdgcn_mfma_f32_16x16x32_bf16(a, b, acc[nt], 0, 0, 0);
            }
        }
    }

    int colb = lane & 15;
    int rowe = rowbase + wave * 16 + (lane >> 4) * 4;
#pragma unroll
    for (int nt = 0; nt < 8; nt++) {
#pragma unroll
        for (int r = 0; r < 4; r++) {
            int row = rowe + r;
            if (row < ndst)
                out[(size_t)(outrow0 + row) * 256 + 128 + nt * 16 + colb] =
                    fmaxf(acc[nt][r] * scale, 0.f);
        }
    }
}

extern "C" void kernel_launch(void* const* d_in, const int* in_sizes, int n_in,
                              void* d_out, int out_size, void* d_ws, size_t ws_size,
                              hipStream_t stream) {
    const float* opf  = (const float*)d_in[0];
    const float* devf = (const float*)d_in[1];
    const float* ef[5]; const int* src[5]; const int* dst[5];
    const float* W[5]; const float* bias[5];
    int ne[5];
    for (int i = 0; i < 5; i++) {
        ef[i]   = (const float*)d_in[2 + 5 * i + 0];
        src[i]  = (const int*)  d_in[2 + 5 * i + 1];
        dst[i]  = (const int*)  d_in[2 + 5 * i + 2];
        W[i]    = (const float*)d_in[2 + 5 * i + 3];
        bias[i] = (const float*)d_in[2 + 5 * i + 4];
        ne[i]   = in_sizes[2 + 5 * i + 1];
    }
    int e1 = ne[0], e2 = e1 + ne[1], e3 = e2 + ne[2], e4 = e3 + ne[3];
    int ntot = e4 + ne[4];
    int ntot_pad = (ntot + 1) & ~1;
    int nblk = (ntot + CHUNK - 1) / CHUNK;

    char* wp = (char*)d_ws;
    int* bstart = (int*)wp;  wp += (size_t)(NBUCK + 1) * 4;
    int* totals = (int*)wp;  wp += (size_t)NBUCK * 4;
    wp += 4;                                   // align to 8
    int* hist   = (int*)wp;  wp += (size_t)nblk * NBUCK * 4;
    wp = (char*)(((size_t)wp + 7) & ~7);
    int2* edata = (int2*)wp; wp += (size_t)ntot_pad * 8;
    u16* aggb   = (u16*)wp;  wp += (size_t)N_NODES * 160 * 2;
    u8* opb     = (u8*)wp;   wp += (size_t)N_OP * 128;
    u8* devb    = (u8*)wp;   wp += (size_t)N_DEV * 128;
    u8* efb8    = (u8*)wp;   wp += (size_t)ntot_pad * 16;
    u16* wtop   = (u16*)wp;  wp += (size_t)128 * 480 * 2;
    u16* wtdev  = (u16*)wp;
    float* out  = (float*)d_out;

    const int NU = (N_OP + N_DEV) * 32 + 128 * 800;  // feats quads + wt units
    prep_kernel<<<(NU + 4 * ntot + 255) / 256, 256, 0, stream>>>(
        opf, devf, W[0], W[1], W[2], W[3], W[4],
        bias[0], bias[1], bias[2], bias[3], bias[4],
        ef[0], ef[1], ef[2], ef[3], ef[4],
        e1, e2, e3, e4, ntot, opb, devb, efb8, out, wtop, wtdev);

    binA_count_kernel<<<nblk, 1024, 0, stream>>>(
        dst[0], dst[1], dst[2], dst[3], dst[4],
        e1, e2, e3, e4, ntot, hist);

    scanS1_kernel<<<(NBUCK + 255) / 256, 256, 0, stream>>>(hist, totals, nblk);
    scanS2_kernel<<<1, 1024, 0, stream>>>(totals, bstart);

    binA_place_kernel<<<nblk, 1024, 0, stream>>>(
        src[0], src[1], src[2], src[3], src[4],
        dst[0], dst[1], dst[2], dst[3], dst[4],
        e1, e2, e3, e4, ntot, hist, bstart, edata);

    agg_fused_kernel<<<NBUCK, 512, 0, stream>>>(
        opb, devb, efb8, edata, bstart, aggb);

    int opblocks = (N_OP + 63) / 64, devblocks = (N_DEV + 63) / 64;
    gemm_mfma_kernel<<<opblocks + devblocks, 256, 0, stream>>>(
        aggb, wtop, wtdev, out, opblocks);
    (void)n_in; (void)out_size; (void)ws_size;
}